// Round 4
// baseline (341.883 us; speedup 1.0000x reference)
//
#include <hip/hip_runtime.h>
#include <math.h>

#define NB 32
#define NP 24656
#define NO 16
#define NC 81
#define ND 85   // 4 + NC
#define THRESH_F 0.5f
#define NEGPOS_I 3
#define VAR0_F 0.1f
#define VAR1_F 0.2f
#define NEG_HUGE -1e30f

#define BPCNT (NB * NP)

// ---------------------------------------------------------------- init
__global__ void k_init(unsigned long long* __restrict__ bpk,
                       int* __restrict__ npos,
                       float* __restrict__ accB) {
    int t = blockIdx.x * blockDim.x + threadIdx.x;
    if (t < NB * NO) bpk[t] = 0ull;
    if (t < NB) npos[t] = 0;
    if (t < 2 * NB) accB[t] = 0.f;
}

// ---------------------------------------------------------------- match
__global__ __launch_bounds__(256) void k_match(
    const float* __restrict__ tboxes, const float* __restrict__ priors,
    float* __restrict__ bto, int* __restrict__ bti,
    unsigned long long* __restrict__ bpk) {
    const int b = blockIdx.y;
    const int p = blockIdx.x * 256 + threadIdx.x;
    const int lane = threadIdx.x & 63;
    __shared__ float tb[NO * 4];
    if (threadIdx.x < NO * 4) tb[threadIdx.x] = tboxes[b * NO * 4 + threadIdx.x];
    __syncthreads();

    const bool valid = (p < NP);
    float4 pr = make_float4(0.f, 0.f, 1.f, 1.f);
    if (valid) pr = *(const float4*)(priors + (size_t)p * 4);
    const float pl = pr.x - pr.z * 0.5f, pt = pr.y - pr.w * 0.5f;
    const float prr = pr.x + pr.z * 0.5f, pb = pr.y + pr.w * 0.5f;
    const float parea = (prr - pl) * (pb - pt);

    float bestv = -1.f;
    int besti = 0;
    for (int o = 0; o < NO; ++o) {
        const float al = tb[o * 4 + 0], at = tb[o * 4 + 1];
        const float ar = tb[o * 4 + 2], ab = tb[o * 4 + 3];
        float iw = fminf(ar, prr) - fmaxf(al, pl); iw = fmaxf(iw, 0.f);
        float ih = fminf(ab, pb) - fmaxf(at, pt); ih = fmaxf(ih, 0.f);
        const float inter = iw * ih;
        const float aarea = (ar - al) * (ab - at);
        float iou = inter / (aarea + parea - inter);
        if (!valid) iou = -1.f;
        if (iou > bestv) { bestv = iou; besti = o; }

        float m = iou;
        for (int d = 1; d < 64; d <<= 1) m = fmaxf(m, __shfl_xor(m, d, 64));
        if (m >= 0.f) {
            unsigned long long msk = __ballot(iou == m);
            int lam = __ffsll(msk) - 1;
            int pw = blockIdx.x * 256 + (threadIdx.x & ~63) + lam;
            if (lane == 0) {
                unsigned long long key =
                    ((unsigned long long)__float_as_uint(m) << 32) |
                    (unsigned long long)(0xFFFFFFFFu - (unsigned)pw);
                atomicMax(&bpk[b * NO + o], key);
            }
        }
    }
    if (valid) {
        bto[(size_t)b * NP + p] = bestv;
        bti[(size_t)b * NP + p] = besti;
    }
}

// ---------------------------------------------------------------- scatter
__global__ void k_scatter(const unsigned long long* __restrict__ bpk,
                          float* __restrict__ bto, int* __restrict__ bti) {
    int b = blockIdx.x * blockDim.x + threadIdx.x;
    if (b >= NB) return;
    for (int o = 0; o < NO; ++o) {
        unsigned long long key = bpk[b * NO + o];
        int p = (int)(0xFFFFFFFFu - (unsigned)(key & 0xFFFFFFFFull));
        bto[(size_t)b * NP + p] = 2.0f;
        bti[(size_t)b * NP + p] = o;
    }
}

// ---------------------------------------------------------------- main fused
// Lane-per-row, FULL register prefetch: all 22 aligned float4 loads issued
// back-to-back (one latency wait instead of 21), then max-tree + exp-sum in
// registers. Edge components masked in copies h/t; v[0],v[1] keep loc data.
__global__ __launch_bounds__(256) void k_main(
    const float* __restrict__ pred, const float* __restrict__ tboxes,
    const int* __restrict__ tlabels, const float* __restrict__ priors,
    const float* __restrict__ bto, const int* __restrict__ bti,
    float* __restrict__ lr, int* __restrict__ npos, float* __restrict__ accB) {
    const int b = blockIdx.y;
    const int tid = threadIdx.x;
    const int p = blockIdx.x * 256 + tid;
    const bool valid = (p < NP);
    const int r = valid ? p : (NP - 1);

    const float* base = pred + (size_t)b * NP * ND;  // 16B-aligned
    const int A = 21 * r + (r >> 2);
    const int c0 = r & 3;
    const float4* vp = (const float4*)base + A;

    float4 v[22];
#pragma unroll
    for (int k = 0; k < 22; ++k) v[k] = vp[k];

    // background logit = window dword (c0+4) = v[1][c0]
    const float bg = (c0 == 0) ? v[1].x : (c0 == 1) ? v[1].y
                   : (c0 == 2) ? v[1].z : v[1].w;
    // masked head: window dword j of v[1] invalid if j < c0+4 (component < c0)
    float4 h = v[1];
    h.x = (c0 >= 1) ? NEG_HUGE : h.x;
    h.y = (c0 >= 2) ? NEG_HUGE : h.y;
    h.z = (c0 >= 3) ? NEG_HUGE : h.z;
    // masked tail: v[21] component t invalid iff t > c0
    float4 t = v[21];
    t.y = (c0 < 1) ? NEG_HUGE : t.y;
    t.z = (c0 < 2) ? NEG_HUGE : t.z;
    t.w = (c0 < 3) ? NEG_HUGE : t.w;

    // max over h, v[2..20], t — two independent chains for latency
    float4 MA = h, MB = t;
#pragma unroll
    for (int k = 2; k < 21; k += 2) {
        MA.x = fmaxf(MA.x, v[k].x); MA.y = fmaxf(MA.y, v[k].y);
        MA.z = fmaxf(MA.z, v[k].z); MA.w = fmaxf(MA.w, v[k].w);
    }
#pragma unroll
    for (int k = 3; k < 21; k += 2) {
        MB.x = fmaxf(MB.x, v[k].x); MB.y = fmaxf(MB.y, v[k].y);
        MB.z = fmaxf(MB.z, v[k].z); MB.w = fmaxf(MB.w, v[k].w);
    }
    const float m = fmaxf(fmaxf(fmaxf(MA.x, MB.x), fmaxf(MA.y, MB.y)),
                          fmaxf(fmaxf(MA.z, MB.z), fmaxf(MA.w, MB.w)));

    // exp-sum over the same 21 chunks, two chains
    float sA = 0.f, sB = 0.f;
    {
        sA += __expf(h.x - m) + __expf(h.y - m) + __expf(h.z - m) + __expf(h.w - m);
        sB += __expf(t.x - m) + __expf(t.y - m) + __expf(t.z - m) + __expf(t.w - m);
    }
#pragma unroll
    for (int k = 2; k < 21; k += 2)
        sA += __expf(v[k].x - m) + __expf(v[k].y - m) +
              __expf(v[k].z - m) + __expf(v[k].w - m);
#pragma unroll
    for (int k = 3; k < 21; k += 2)
        sB += __expf(v[k].x - m) + __expf(v[k].y - m) +
              __expf(v[k].z - m) + __expf(v[k].w - m);
    const float lse = m + __logf(sA + sB);

    float btv = 0.f;
    int o = 0;
    if (valid) {
        btv = bto[(size_t)b * NP + p];
        o = bti[(size_t)b * NP + p];
    }
    const bool pos = valid && (btv >= THRESH_F);
    if (valid) lr[(size_t)b * NP + p] = pos ? 0.f : (lse - bg);

    float my_ll = 0.f, my_ce = 0.f;
    int my_np = 0;
    if (pos) {
        my_np = 1;
        const int lbl = tlabels[b * NO + o] + 1;
        const float val = base[(size_t)r * ND + 4 + lbl];  // L1/L2 hit
        my_ce = lse - val;
        const float4 pr = *((const float4*)priors + r);
        const float tx0 = tboxes[(b * NO + o) * 4 + 0];
        const float ty0 = tboxes[(b * NO + o) * 4 + 1];
        const float tx1 = tboxes[(b * NO + o) * 4 + 2];
        const float ty1 = tboxes[(b * NO + o) * 4 + 3];
        // loc = window dwords c0..c0+3 from v[0]/v[1]
        const float l0 = (c0 == 0) ? v[0].x : (c0 == 1) ? v[0].y
                       : (c0 == 2) ? v[0].z : v[0].w;
        const float l1 = (c0 == 0) ? v[0].y : (c0 == 1) ? v[0].z
                       : (c0 == 2) ? v[0].w : v[1].x;
        const float l2 = (c0 == 0) ? v[0].z : (c0 == 1) ? v[0].w
                       : (c0 == 2) ? v[1].x : v[1].y;
        const float l3 = (c0 == 0) ? v[0].w : (c0 == 1) ? v[1].x
                       : (c0 == 2) ? v[1].y : v[1].z;
        const float g0 = ((tx0 + tx1) * 0.5f - pr.x) / (VAR0_F * pr.z);
        const float g1 = ((ty0 + ty1) * 0.5f - pr.y) / (VAR0_F * pr.w);
        const float g2 = __logf((tx1 - tx0) / pr.z) / VAR1_F;
        const float g3 = __logf((ty1 - ty0) / pr.w) / VAR1_F;
        float dd, ad;
        dd = l0 - g0; ad = fabsf(dd); my_ll += (ad < 1.f) ? 0.5f * dd * dd : (ad - 0.5f);
        dd = l1 - g1; ad = fabsf(dd); my_ll += (ad < 1.f) ? 0.5f * dd * dd : (ad - 0.5f);
        dd = l2 - g2; ad = fabsf(dd); my_ll += (ad < 1.f) ? 0.5f * dd * dd : (ad - 0.5f);
        dd = l3 - g3; ad = fabsf(dd); my_ll += (ad < 1.f) ? 0.5f * dd * dd : (ad - 0.5f);
    }
    for (int d2 = 1; d2 < 64; d2 <<= 1) {
        my_ll += __shfl_xor(my_ll, d2, 64);
        my_ce += __shfl_xor(my_ce, d2, 64);
        my_np += __shfl_xor(my_np, d2, 64);
    }
    if ((tid & 63) == 0) {
        if (my_ll != 0.f) atomicAdd(&accB[b * 2 + 0], my_ll);
        if (my_ce != 0.f) atomicAdd(&accB[b * 2 + 1], my_ce);
        if (my_np) atomicAdd(&npos[b], my_np);
    }
}

// ---------------------------------------------------------------- select
__global__ __launch_bounds__(1024) void k_select(
    const float* __restrict__ lrk, const int* __restrict__ npos,
    float* __restrict__ accB) {
    const int b = blockIdx.x;
    const float* row = lrk + (size_t)b * NP;
    const int tid = threadIdx.x;
    const int lane = tid & 63;
    const int wid = tid >> 6;

    __shared__ unsigned whist[16][256];
    __shared__ unsigned chist[256];
    __shared__ int sh_bucket, sh_knew;
    __shared__ float wsum[16];
    __shared__ int wcnt[16];

    const int K0 = min(npos[b] * NEGPOS_I, NP);
    int k = K0;
    unsigned prefix = 0;

    for (int shift = 24; shift >= 0; shift -= 8) {
        for (int j = lane; j < 256; j += 64) whist[wid][j] = 0;
        __syncthreads();
        const unsigned mask_hi = (shift == 24) ? 0u : (0xFFFFFFFFu << (shift + 8));
        for (int i = tid; i < NP; i += 1024) {
            unsigned v = __float_as_uint(row[i]);
            if ((v & mask_hi) == (prefix & mask_hi))
                atomicAdd(&whist[wid][(v >> shift) & 0xFFu], 1u);
        }
        __syncthreads();
        if (tid < 256) {
            unsigned t = 0;
            for (int w = 0; w < 16; ++w) t += whist[w][tid];
            chist[tid] = t;
        }
        __syncthreads();
        if (tid < 64) {
            const unsigned cA = chist[4 * lane + 0];
            const unsigned cB = chist[4 * lane + 1];
            const unsigned cC = chist[4 * lane + 2];
            const unsigned cD = chist[4 * lane + 3];
            const unsigned g = cA + cB + cC + cD;
            unsigned T = g;
            for (int d = 1; d < 64; d <<= 1) {
                unsigned t = __shfl_down(T, d, 64);
                if (lane + d < 64) T += t;
            }
            const unsigned E = T - g;
            const bool hit = (E < (unsigned)k) && ((unsigned)k <= T);
            unsigned long long msk = __ballot(hit);
            int wl = __ffsll(msk) - 1;
            if (lane == wl) {
                unsigned cum = E;
                int bsel = 4 * lane;
                int kn = k;
                const unsigned cc[4] = {cD, cC, cB, cA};
                for (int j = 0; j < 4; ++j) {
                    if (cum + cc[j] >= (unsigned)k) {
                        bsel = 4 * lane + 3 - j;
                        kn = k - (int)cum;
                        break;
                    }
                    cum += cc[j];
                }
                sh_bucket = bsel;
                sh_knew = kn;
            }
        }
        __syncthreads();
        prefix |= ((unsigned)sh_bucket) << shift;
        k = sh_knew;
        __syncthreads();
    }
    const float T = __uint_as_float(prefix);

    float msum = 0.f;
    int mcnt = 0;
    for (int i = tid; i < NP; i += 1024) {
        float v = row[i];
        if (__float_as_uint(v) > prefix) { msum += v; mcnt++; }
    }
    for (int s = 32; s > 0; s >>= 1) {
        msum += __shfl_down(msum, s, 64);
        mcnt += __shfl_down(mcnt, s, 64);
    }
    if (lane == 0) { wsum[wid] = msum; wcnt[wid] = mcnt; }
    __syncthreads();
    if (tid == 0) {
        float tot = 0.f;
        int cnt = 0;
        for (int w = 0; w < 16; ++w) { tot += wsum[w]; cnt += wcnt[w]; }
        atomicAdd(&accB[b * 2 + 1], tot + (float)(K0 - cnt) * T);
    }
}

// ---------------------------------------------------------------- final
__global__ void k_final(const int* __restrict__ npos,
                        const float* __restrict__ accB,
                        float* __restrict__ out) {
    if (threadIdx.x == 0 && blockIdx.x == 0) {
        int n = 0;
        float a0 = 0.f, a1 = 0.f;
        for (int b = 0; b < NB; ++b) {
            n += npos[b];
            a0 += accB[b * 2 + 0];
            a1 += accB[b * 2 + 1];
        }
        const float N = (float)n;
        out[0] = a0 / N;
        out[1] = a1 / N;
    }
}

extern "C" void kernel_launch(void* const* d_in, const int* in_sizes, int n_in,
                              void* d_out, int out_size, void* d_ws, size_t ws_size,
                              hipStream_t stream) {
    const float* pred   = (const float*)d_in[0];
    const float* tboxes = (const float*)d_in[1];
    const int*   tlabels = (const int*)d_in[2];
    const float* priors = (const float*)d_in[3];
    float* out = (float*)d_out;

    char* w = (char*)d_ws;
    float* bto = (float*)w;                                   // BPCNT f32
    int*   bti = (int*)(w + 4ull * BPCNT);                    // BPCNT i32
    float* lrk = (float*)(w + 8ull * BPCNT);                  // BPCNT f32
    unsigned long long* bpk =
        (unsigned long long*)(w + 12ull * BPCNT);             // NB*NO u64
    int* npos = (int*)(w + 12ull * BPCNT + 8ull * NB * NO);   // NB i32
    float* accB = (float*)(w + 12ull * BPCNT + 8ull * NB * NO + 4ull * NB); // NB*2

    k_init<<<dim3(2), dim3(256), 0, stream>>>(bpk, npos, accB);
    k_match<<<dim3((NP + 255) / 256, NB), dim3(256), 0, stream>>>(
        tboxes, priors, bto, bti, bpk);
    k_scatter<<<dim3(1), dim3(64), 0, stream>>>(bpk, bto, bti);
    k_main<<<dim3((NP + 255) / 256, NB), dim3(256), 0, stream>>>(
        pred, tboxes, tlabels, priors, bto, bti, lrk, npos, accB);
    k_select<<<dim3(NB), dim3(1024), 0, stream>>>(lrk, npos, accB);
    k_final<<<dim3(1), dim3(1), 0, stream>>>(npos, accB, out);
}